// Round 2
// baseline (362.255 us; speedup 1.0000x reference)
//
#include <hip/hip_runtime.h>

// Triline interp, LDS-staged variant.
// B=1M points, N=512, C=64 fp32. Out = 256 MB (HBM floor ~42 us).
// Round-1 bottleneck: 1.5 GB of line gathers through L1/L2 (tables 384 KiB >> 32 KiB L1).
// Fix: 4 channel-groups x 16ch; each block stages its slice of all 3 tables into
// LDS as bf16 (3 x 512 x 40 B = 60 KiB static), gathers become ds_read_b64.
// Padded row stride 40 B (10 dw, gcd(10,32)=2 -> 16 bank-start classes, ~conflict-free).
// 4 lanes/point -> 64 B contiguous stores per point (full cache lines).

typedef float f4 __attribute__((ext_vector_type(4)));
typedef unsigned short u16;
typedef u16 us4 __attribute__((ext_vector_type(4)));

constexpr int kN        = 512;
constexpr int kC4       = 16;   // C/4 float4 chunks per full row
constexpr int kGroups   = 4;    // channel groups of 16
constexpr int kStride   = 20;   // LDS row stride in u16 units (40 B: 32 B data + 8 B pad)
constexpr int kParts    = 128;  // point partitions
constexpr int kThreads  = 1024;

__device__ __forceinline__ u16 f32_to_bf16_rn(float f) {
    unsigned int u = __builtin_bit_cast(unsigned int, f);
    unsigned int r = (u + 0x7FFFu + ((u >> 16) & 1u)) >> 16;
    return (u16)r;
}
__device__ __forceinline__ float bf16_to_f32(u16 h) {
    unsigned int u = ((unsigned int)h) << 16;
    return __builtin_bit_cast(float, u);
}
__device__ __forceinline__ f4 us4_to_f4(us4 h) {
    f4 r;
    r.x = bf16_to_f32(h.x); r.y = bf16_to_f32(h.y);
    r.z = bf16_to_f32(h.z); r.w = bf16_to_f32(h.w);
    return r;
}

__global__ __launch_bounds__(kThreads) void triline_kernel(
    const float* __restrict__ coords,
    const f4* __restrict__ xl,
    const f4* __restrict__ yl,
    const f4* __restrict__ zl,
    const float* __restrict__ grid,
    f4* __restrict__ out,
    int B)
{
    __shared__ u16 s_tab[3 * kN * kStride];   // 60 KiB

    const int tid   = threadIdx.x;
    const int g     = blockIdx.x & (kGroups - 1);   // channel group 0..3
    const int part  = blockIdx.x >> 2;              // point partition 0..127
    const int pts   = B / kParts;
    const int pbase = part * pts;

    // ---- stage: this block's 16-channel slice of x/y/z tables -> bf16 in LDS
    // 3 tables * 512 rows * 4 f4-chunks = 6144 f4 loads across the block.
    for (int s = tid; s < 3 * kN * 4; s += kThreads) {
        int t  = s >> 11;        // table 0..2  (512*4 = 2048 per table)
        int rq = s & 2047;
        int r  = rq >> 2;        // row
        int q  = rq & 3;         // f4 chunk within the 16-ch slice
        const f4* tp = (t == 0) ? xl : ((t == 1) ? yl : zl);
        f4 v = tp[r * kC4 + g * 4 + q];
        us4 h;
        h.x = f32_to_bf16_rn(v.x); h.y = f32_to_bf16_rn(v.y);
        h.z = f32_to_bf16_rn(v.z); h.w = f32_to_bf16_rn(v.w);
        *(us4*)&s_tab[t * (kN * kStride) + r * kStride + q * 4] = h;
    }

    float g0     = grid[0];
    float inv_dg = 1.0f / (grid[1] - g0);

    __syncthreads();

    const u16* sx = &s_tab[0];
    const u16* sy = &s_tab[kN * kStride];
    const u16* sz = &s_tab[2 * kN * kStride];

    const int items = pts * 4;          // (point, chunk) pairs; chunk = 4 channels
    for (int i = tid; i < items; i += kThreads) {
        int p = pbase + (i >> 2);
        int c = i & 3;
        if (p >= B) break;

        float cx = coords[3 * p + 0];
        float cy = coords[3 * p + 1];
        float cz = coords[3 * p + 2];

        float px = (cx - g0) * inv_dg;
        float py = (cy - g0) * inv_dg;
        float pz = (cz - g0) * inv_dg;

        int ix = min(max((int)floorf(px), 0), kN - 2);
        int iy = min(max((int)floorf(py), 0), kN - 2);
        int iz = min(max((int)floorf(pz), 0), kN - 2);

        float wx = px - (float)ix;
        float wy = py - (float)iy;
        float wz = pz - (float)iz;

        const u16* ax = sx + ix * kStride + c * 4;
        const u16* ay = sy + iy * kStride + c * 4;
        const u16* az = sz + iz * kStride + c * 4;

        f4 x0 = us4_to_f4(*(const us4*)ax);
        f4 x1 = us4_to_f4(*(const us4*)(ax + kStride));
        f4 y0 = us4_to_f4(*(const us4*)ay);
        f4 y1 = us4_to_f4(*(const us4*)(ay + kStride));
        f4 z0 = us4_to_f4(*(const us4*)az);
        f4 z1 = us4_to_f4(*(const us4*)(az + kStride));

        f4 r = x0 + (x1 - x0) * wx;
        r    = r + y0 + (y1 - y0) * wy;
        r    = r + z0 + (z1 - z0) * wz;

        out[p * kC4 + g * 4 + c] = r;
    }
}

extern "C" void kernel_launch(void* const* d_in, const int* in_sizes, int n_in,
                              void* d_out, int out_size, void* d_ws, size_t ws_size,
                              hipStream_t stream) {
    const float* coords = (const float*)d_in[0];
    const f4*    xl     = (const f4*)d_in[1];
    const f4*    yl     = (const f4*)d_in[2];
    const f4*    zl     = (const f4*)d_in[3];
    const float* grid   = (const float*)d_in[4];
    f4*          out    = (f4*)d_out;

    int B = in_sizes[0] / 3;   // 1048576

    dim3 grid_dim(kGroups * kParts);   // 512 blocks: 4 channel groups x 128 partitions
    triline_kernel<<<grid_dim, kThreads, 0, stream>>>(coords, xl, yl, zl, grid, out, B);
}